// Round 6
// baseline (148.548 us; speedup 1.0000x reference)
//
#include <hip/hip_runtime.h>
#include <hip/hip_bf16.h>
#include <cfloat>
#include <math.h>

#define N_TOK   32768
#define S_CODES 1024
#define C_DIM   256

typedef __attribute__((ext_vector_type(8))) short short8v;
typedef __attribute__((ext_vector_type(4))) float float4v;

// ---- workspace byte offsets ----
#define WS_HIST 0                       // 1024 int
#define WS_LOSS 4096                    // 1 float
#define WS_W2   4608                    // 1024 float
#define WS_WPK  16384                   // w_packed [1024 codes][8 kc][hi 64B | lo 64B] = 1 MB
#define WS_NEED ((size_t)(WS_WPK + 1048576))

__device__ __forceinline__ unsigned short f2bf(float f) {
    __hip_bfloat16 h = __float2bfloat16(f);
    return __builtin_bit_cast(unsigned short, h);
}
__device__ __forceinline__ float bf2f(unsigned short u) {
    return __bfloat162float(__builtin_bit_cast(__hip_bfloat16, u));
}
__device__ __forceinline__ void gload16(const void* g, void* l) {
    __builtin_amdgcn_global_load_lds((const __attribute__((address_space(1))) void*)g,
                                     (__attribute__((address_space(3))) void*)l, 16, 0, 0);
}

// ---- split w into packed hi/lo rows + squared norms; also zero hist/loss ----
__global__ void split_w(const float* __restrict__ w, unsigned short* __restrict__ wpack,
                        float* __restrict__ w2, int* __restrict__ hist,
                        float* __restrict__ lossp) {
    int c = blockIdx.x, l = threadIdx.x;       // 1024 blocks x 64 threads
    float4 v = ((const float4*)(w + (size_t)c * C_DIM))[l];   // k = l*4 .. +3
    float s = v.x*v.x + v.y*v.y + v.z*v.z + v.w*v.w;
    float vv[4] = {v.x, v.y, v.z, v.w};
    ushort4 h4, l4;
    unsigned short* hp = (unsigned short*)&h4;
    unsigned short* lp = (unsigned short*)&l4;
#pragma unroll
    for (int q = 0; q < 4; ++q) {
        hp[q] = f2bf(vv[q]);
        lp[q] = f2bf(vv[q] - bf2f(hp[q]));
    }
    size_t base = ((size_t)c * 8 + (l >> 3)) * 64;            // 64 shorts = 128 B per (c,kc)
    *(ushort4*)&wpack[base + (l & 7) * 4] = h4;               // hi half (bytes 0..63)
    *(ushort4*)&wpack[base + 32 + (l & 7) * 4] = l4;          // lo half (bytes 64..127)
#pragma unroll
    for (int off = 32; off > 0; off >>= 1) s += __shfl_down(s, off);
    if (l == 0) w2[c] = s;
    if (l == 32) hist[c] = 0;
    if (c == 0 && l == 33) *lossp = 0.f;
}

// ---- main: 64-token blocks (512 blocks), 8 waves; wave w owns codes [w*128,(w+1)*128).
//      BARRIER-FREE K-loop: W staged wave-PRIVATELY via global_load_lds into a
//      per-wave ring of 3x4KB half-buffers, self-synced by counted vmcnt (8/8,
//      tail 4/0) + one lgkmcnt(0)/step for WAR reuse. Waves drift apart freely ->
//      LDS and MFMA pipes overlap via TLP, no scheduler cooperation needed.
//      Wave tile 64 tok x 64 codes: per kc-step 16 ds_read_b128 / 48 MFMA.
//      LDS: xh 32K | xl 32K | ring 8x12K = 163840 B exactly. ----
__global__ void __launch_bounds__(512, 2)
vq_fused7(const float* __restrict__ x, const float* __restrict__ emb,
          const unsigned short* __restrict__ wpack, const float* __restrict__ w2g,
          float* __restrict__ out, int* __restrict__ hist, float* __restrict__ lossp) {
    __shared__ __align__(16) char smem[163840];
    unsigned short* xh = (unsigned short*)smem;               // [64 tok][256 k] bf16 hi
    unsigned short* xl = (unsigned short*)(smem + 32768);     // lo
    char* ring = smem + 65536;                                // 8 waves x 3 x 4 KB
    char* scr  = smem + 65536;                                // phase-3 overlay

    const int tid = threadIdx.x;
    const int l = tid & 63, wv = tid >> 6;
    const int quad = l >> 4, lr = l & 15;
    const int t0 = blockIdx.x * 64;
    const int b = t0 >> 10, hw0 = t0 & 1023;
    const size_t xbase = ((size_t)b << 18) + hw0;

    const int wbase = wv * 128;               // this wave's code range
    const int drq = l >> 3;                   // DMA: row within 8-row group
    const int dch = (l & 7) ^ (drq & 7);      // source chunk (un-swizzle)
    const char* wpc = (const char*)wpack;
    char* rb = ring + wv * 12288;             // private ring base

    // stage half h (32 codes, one kc) into given slot; 4 gloads x 1 KB
    auto STAGE = [&](int h, char* slot) {
        int gg = h >> 1;
        int c0 = wbase + ((gg >> 3) << 6) + ((h & 1) << 5);
        int kcp = gg & 7;
#pragma unroll
        for (int u = 0; u < 4; ++u) {
            int code = c0 + u * 8 + drq;
            size_t src = ((size_t)code * 8 + kcp) * 128 + (size_t)dch * 16;
            gload16(wpc + src, slot + u * 1024);
        }
    };

    // w2 preload (8 scalar loads; retire during phase 1, keep K-loop vmem clean)
    float w2v[2][4];
#pragma unroll
    for (int ct = 0; ct < 2; ++ct)
#pragma unroll
        for (int jj = 0; jj < 4; ++jj)
            w2v[ct][jj] = w2g[wbase + ct * 64 + jj * 16 + lr];

    // first two halves' DMA in flight under all of phase 1
    STAGE(0, rb);
    STAGE(1, rb + 4096);

    // ---- phase 1: convert x (barrier-free, coalesced). thread = (token ctk, k-block kq8)
    float x2p = 0.f;                          // partial |x|^2 over this thread's 32 k
    {
        const int ctk = tid & 63, kq8 = tid >> 6;
#pragma unroll 1
        for (int c4 = 0; c4 < 4; ++c4) {
            int ch = kq8 * 4 + c4;            // 16B-chunk index 0..31 (k = ch*8..+7)
            const float* gp = x + xbase + (size_t)(ch * 8) * 1024 + ctk;
            float v8[8];
#pragma unroll
            for (int j2 = 0; j2 < 8; ++j2) v8[j2] = gp[(size_t)j2 * 1024];
            short8v hv, lv;
#pragma unroll
            for (int j2 = 0; j2 < 8; ++j2) {
                float v = v8[j2];
                unsigned short h = f2bf(v);
                float hf = bf2f(h);
                unsigned short lo = f2bf(v - hf);
                hv[j2] = (short)h; lv[j2] = (short)lo;
                x2p = fmaf(v, v, x2p);
            }
            int pos = ch ^ (ctk & 31);        // XOR swizzle, 16B chunks
            *(short8v*)&xh[ctk * 256 + pos * 8] = hv;
            *(short8v*)&xl[ctk * 256 + pos * 8] = lv;
        }
    }
    __syncthreads();                          // xh/xl ready (immutable afterwards)

    // ---- precomputed fragment offsets ----
    int aoffb[4], axor[4];
#pragma unroll
    for (int i = 0; i < 4; ++i) {
        int arow = i * 16 + lr;               // token row 0..63
        aoffb[i] = arow * 512;                // bytes (row = 256 shorts)
        axor[i] = arow & 31;
    }
    int boff_h[2], boff_l[2];
#pragma unroll
    for (int j = 0; j < 2; ++j) {
        int brow = j * 16 + lr;               // row within 32-code half, 128 B rows
        boff_h[j] = brow * 128 + ((quad ^ (brow & 7)) * 16);
        boff_l[j] = brow * 128 + (((4 + quad) ^ (brow & 7)) * 16);
    }

    float bval[16]; int bidx[16];
#pragma unroll
    for (int s2 = 0; s2 < 16; ++s2) { bval[s2] = FLT_MAX; bidx[s2] = 0; }
    const float4v zacc = {0.f, 0.f, 0.f, 0.f};

    // ---- phase 2: 16 steps (2 ct x 8 kc), wave-private ring, zero barriers ----
    int sA = 0;                               // ring slot of half h0=2g
#pragma unroll 1
    for (int ct = 0; ct < 2; ++ct) {
        float4v acc[4][4];
#pragma unroll
        for (int i = 0; i < 4; ++i)
#pragma unroll
            for (int j = 0; j < 4; ++j) acc[i][j] = zacc;

#pragma unroll 1
        for (int kc = 0; kc < 8; ++kc) {
            const int g = ct * 8 + kc;
            int sB = sA + 1; if (sB > 2) sB = 0;
            int sC = sB + 1; if (sC > 2) sC = 0;
            char* bufA = rb + sA * 4096;      // half 2g
            char* bufB = rb + sB * 4096;      // half 2g+1

            if (g < 15) {
                STAGE(2 * g + 2, rb + sC * 4096);   // slot(2g+2)=slot(2g-1): consumed last step
                asm volatile("s_waitcnt vmcnt(8)" ::: "memory");   // half 2g landed
            } else {
                asm volatile("s_waitcnt vmcnt(4)" ::: "memory");
            }
            // read B half0 + A (normal ds_reads; compiler tracks deps)
            short8v bh0[2], bl0[2], ah[4], al[4];
#pragma unroll
            for (int j = 0; j < 2; ++j) {
                bh0[j] = *(const short8v*)(bufA + boff_h[j]);
                bl0[j] = *(const short8v*)(bufA + boff_l[j]);
            }
#pragma unroll
            for (int i = 0; i < 4; ++i) {
                int pos = ((kc * 4 + quad) ^ axor[i]) * 16;
                ah[i] = *(const short8v*)(smem + aoffb[i] + pos);
                al[i] = *(const short8v*)(smem + 32768 + aoffb[i] + pos);
            }
            asm volatile("s_waitcnt lgkmcnt(0)" ::: "memory");     // all reads landed (WAR-safe)
            if (g < 15) {
                STAGE(2 * g + 3, rb + sA * 4096);   // reuses slot(2g) — reads retired above
                asm volatile("s_waitcnt vmcnt(8)" ::: "memory");   // half 2g+1 landed
            } else {
                asm volatile("s_waitcnt vmcnt(0)" ::: "memory");
            }
            short8v bh1[2], bl1[2];
#pragma unroll
            for (int j = 0; j < 2; ++j) {
                bh1[j] = *(const short8v*)(bufB + boff_h[j]);
                bl1[j] = *(const short8v*)(bufB + boff_l[j]);
            }
            __builtin_amdgcn_s_setprio(1);
#pragma unroll
            for (int i = 0; i < 4; ++i)
#pragma unroll
                for (int j = 0; j < 2; ++j) {
                    acc[i][j] = __builtin_amdgcn_mfma_f32_16x16x32_bf16(ah[i], bh0[j], acc[i][j], 0, 0, 0);
                    acc[i][j] = __builtin_amdgcn_mfma_f32_16x16x32_bf16(ah[i], bl0[j], acc[i][j], 0, 0, 0);
                    acc[i][j] = __builtin_amdgcn_mfma_f32_16x16x32_bf16(al[i], bh0[j], acc[i][j], 0, 0, 0);
                }
#pragma unroll
            for (int i = 0; i < 4; ++i)
#pragma unroll
                for (int j = 0; j < 2; ++j) {
                    acc[i][j+2] = __builtin_amdgcn_mfma_f32_16x16x32_bf16(ah[i], bh1[j], acc[i][j+2], 0, 0, 0);
                    acc[i][j+2] = __builtin_amdgcn_mfma_f32_16x16x32_bf16(ah[i], bl1[j], acc[i][j+2], 0, 0, 0);
                    acc[i][j+2] = __builtin_amdgcn_mfma_f32_16x16x32_bf16(al[i], bh1[j], acc[i][j+2], 0, 0, 0);
                }
            __builtin_amdgcn_s_setprio(0);
            sA = sC;                          // h0 advances by 2 -> slot +2 mod 3
        }
        // fold this ct's 64 codes into running per-token argmin
#pragma unroll
        for (int j = 0; j < 4; ++j) {
            int code = wbase + ct * 64 + j * 16 + lr;
            float w2c = w2v[ct][j];
#pragma unroll
            for (int i = 0; i < 4; ++i)
#pragma unroll
                for (int rr = 0; rr < 4; ++rr) {
                    float sv = fmaf(-2.f, acc[i][j][rr], w2c);
                    int slot = i * 4 + rr;
                    if (sv < bval[slot]) { bval[slot] = sv; bidx[slot] = code; }
                }
        }
    }

    // ---- phase 3: argmin reduce, histogram, loss, gather/write ----
    __syncthreads();                          // all waves done; ring -> scratch
    float* bestv = (float*)scr;               // [8][64]
    int*   besti = (int*)(scr + 2048);        // [8][64]
    int*   idx_sh = (int*)(scr + 4096);       // [64]
    float* x2sh  = (float*)(scr + 4352);      // [8][64]
    x2sh[tid] = x2p;                          // tid = kq8*64 + ctk
#pragma unroll
    for (int slot = 0; slot < 16; ++slot) {
        float bv = bval[slot]; int bi = bidx[slot];
#pragma unroll
        for (int off = 1; off < 16; off <<= 1) {
            float ov = __shfl_xor(bv, off);
            int   oi = __shfl_xor(bi, off);
            if (ov < bv || (ov == bv && oi < bi)) { bv = ov; bi = oi; }
        }
        if (lr == 0) {
            int tloc = (slot >> 2) * 16 + quad * 4 + (slot & 3);   // token 0..63
            bestv[wv * 64 + tloc] = bv; besti[wv * 64 + tloc] = bi;
        }
    }
    __syncthreads();
    if (tid < 64) {
        float bv = bestv[tid]; int bi = besti[tid];
#pragma unroll
        for (int w = 1; w < 8; ++w) {
            float ov = bestv[w * 64 + tid];
            int   oi = besti[w * 64 + tid];
            if (ov < bv || (ov == bv && oi < bi)) { bv = ov; bi = oi; }
        }
        idx_sh[tid] = bi;
        atomicAdd(&hist[bi], 1);
        float x2tok = 0.f;
#pragma unroll
        for (int w = 0; w < 8; ++w) x2tok += x2sh[w * 64 + tid];
        float lsum = bv + x2tok;              // |q-x|^2 = (w2 - 2 q.x) + x^2
#pragma unroll
        for (int off = 32; off > 0; off >>= 1) lsum += __shfl_down(lsum, off);
        if (tid == 0) atomicAdd(lossp, lsum);
    }
    __syncthreads();
    {
        int t = tid & 63, cg = tid >> 6;      // 8 dim-groups of 32
        int id = idx_sh[t];
        const float* erow = emb + (size_t)id * C_DIM;
        float* ob = out + xbase + t;
#pragma unroll
        for (int m4 = 0; m4 < 8; ++m4) {
            int c4 = cg * 32 + m4 * 4;
            float4 q4 = *(const float4*)&erow[c4];
            ob[(size_t)(c4 + 0) * 1024] = q4.x;
            ob[(size_t)(c4 + 1) * 1024] = q4.y;
            ob[(size_t)(c4 + 2) * 1024] = q4.z;
            ob[(size_t)(c4 + 3) * 1024] = q4.w;
        }
    }
}

__global__ void finalize_kernel(const int* __restrict__ hist, const float* __restrict__ lossp,
                                float* __restrict__ out) {
    __shared__ float red[16];
    int tid = threadIdx.x;                  // 1024 threads
    float p = (float)hist[tid] * (1.f / 32768.f);
    float term = p * logf(p + 1e-6f);
#pragma unroll
    for (int off = 32; off > 0; off >>= 1) term += __shfl_down(term, off);
    if ((tid & 63) == 0) red[tid >> 6] = term;
    __syncthreads();
    if (tid == 0) {
        float s = 0.f;
#pragma unroll
        for (int i = 0; i < 16; ++i) s += red[i];
        out[8388608] = 0.25f * lossp[0] * (1.f / 8388608.f);   // quant_loss
        out[8388609] = expf(-s);                               // perplexity
    }
}

// ---- fallback path (round-1 kernel, known-correct) used only if ws too small ----
__global__ void w2_kernel(const float* __restrict__ w, float* __restrict__ w2) {
    int code = blockIdx.x * blockDim.x + threadIdx.x;
    const float4* r = (const float4*)(w + (size_t)code * C_DIM);
    float s = 0.f;
#pragma unroll 8
    for (int i = 0; i < C_DIM / 4; ++i) {
        float4 v = r[i];
        s += v.x * v.x + v.y * v.y + v.z * v.z + v.w * v.w;
    }
    w2[code] = s;
}

__launch_bounds__(256, 2)
__global__ void vq_main(const float* __restrict__ x, const float* __restrict__ emb,
                        float* __restrict__ out, int* __restrict__ hist,
                        float* __restrict__ lossp, const float* __restrict__ w2) {
    __shared__ float w_lds[8 * S_CODES];
    __shared__ float x_lds[C_DIM * 32];
    const int tid = threadIdx.x;
    const int l = tid & 63, wv = tid >> 6;
    const int t0 = blockIdx.x * 32;
    const int b = t0 >> 10, hw0 = t0 & 1023;
    const float* xbase = x + ((size_t)b * C_DIM << 10) + hw0;
    {
        int rl = tid & 7, r0 = tid >> 3;
        for (int rep = 0; rep < 8; ++rep) {
            int c = rep * 32 + r0;
            float4 v = *(const float4*)(xbase + ((size_t)c << 10) + rl * 4);
            *(float4*)&x_lds[c * 32 + rl * 4] = v;
        }
    }
    float4 pre[8];
#pragma unroll
    for (int m = 0; m < 8; ++m) {
        int fid = m * 256 + tid;
        int code = fid >> 1, kq = fid & 1;
        pre[m] = *(const float4*)(emb + (size_t)code * C_DIM + kq * 4);
    }
    float acc[8][16];
#pragma unroll
    for (int t = 0; t < 8; ++t)
#pragma unroll
        for (int j = 0; j < 16; ++j) acc[t][j] = 0.f;
    __syncthreads();
    for (int chunk = 0; chunk < 32; ++chunk) {
#pragma unroll
        for (int m = 0; m < 8; ++m) {
            int fid = m * 256 + tid;
            int code = fid >> 1, kq = fid & 1;
            float4 v = pre[m];
            w_lds[(kq * 4 + 0) * S_CODES + code] = v.x;
            w_lds[(kq * 4 + 1) * S_CODES + code] = v.y;
            w_lds[(kq * 4 + 2) * S_CODES + code] = v.z;
            w_lds[(kq * 4 + 3) * S_CODES + code] = v.w;
        }
        if (chunk + 1 < 32) {
            int k0n = (chunk + 1) * 8;
#pragma unroll
            for (int m = 0; m < 8; ++m) {
                int fid = m * 256 + tid;
                int code = fid >> 1, kq = fid & 1;
                pre[m] = *(const float4*)(emb + (size_t)code * C_DIM + k0n + kq * 4);
            }
        }
        __syncthreads();
        int k0 = chunk * 8;
#pragma unroll
        for (int kk = 0; kk < 8; ++kk) {
            int k = k0 + kk;
            float4 wq0 = *(const float4*)&w_lds[kk * S_CODES +   0 + l * 4];
            float4 wq1 = *(const float4*)&w_lds[kk * S_CODES + 256 + l * 4];
            float4 wq2 = *(const float4*)&w_lds[kk * S_CODES + 512 + l * 4];
            float4 wq3 = *(const float4*)&w_lds[kk * S_CODES + 768 + l * 4];
            float4 xa = *(const float4*)&x_lds[k * 32 + wv * 8];
            float4 xb = *(const float4*)&x_lds[k * 32 + wv * 8 + 4];
            float xs[8] = {xa.x, xa.y, xa.z, xa.w, xb.x, xb.y, xb.z, xb.w};
            float wvv[16] = {wq0.x, wq0.y, wq0.z, wq0.w, wq1.x, wq1.y, wq1.z, wq1.w,
                             wq2.x, wq2.y, wq2.z, wq2.w, wq3.x, wq3.y, wq3.z, wq3.w};
#pragma unroll
            for (int t = 0; t < 8; ++t) {
                float xv = xs[t];
#pragma unroll
                for (int j = 0; j < 16; ++j) acc[t][j] = fmaf(xv, wvv[j], acc[t][j]);
            }
        }
        __syncthreads();
    }
    float w2v[16];
#pragma unroll
    for (int m = 0; m < 4; ++m) {
        float4 v = *(const float4*)&w2[m * 256 + l * 4];
        w2v[m*4+0] = v.x; w2v[m*4+1] = v.y; w2v[m*4+2] = v.z; w2v[m*4+3] = v.w;
    }
    int* idx_sh = (int*)w_lds;
    float* red = (float*)(w_lds + 64);
#pragma unroll
    for (int t = 0; t < 8; ++t) {
        float bv = FLT_MAX; int bi = 0;
#pragma unroll
        for (int m = 0; m < 4; ++m)
#pragma unroll
            for (int j = 0; j < 4; ++j) {
                float s = w2v[m*4+j] - 2.f * acc[t][m*4+j];
                int c = m * 256 + l * 4 + j;
                if (s < bv) { bv = s; bi = c; }
            }
#pragma unroll
        for (int off = 32; off > 0; off >>= 1) {
            float ov = __shfl_xor(bv, off);
            int oi = __shfl_xor(bi, off);
            if (ov < bv || (ov == bv && oi < bi)) { bv = ov; bi = oi; }
        }
        if (l == 0) idx_sh[wv * 8 + t] = bi;
    }
    __syncthreads();
    if (tid < 32) atomicAdd(&hist[idx_sh[tid]], 1);
    float lsum = 0.f;
    for (int e = tid; e < C_DIM * 32; e += 256) {
        int t = e & 31, c = e >> 5;
        int id = idx_sh[t];
        float q = emb[(size_t)id * C_DIM + c];
        float xv = x_lds[c * 32 + t];
        float d = q - xv;
        lsum += d * d;
        out[((size_t)(b * C_DIM + c) << 10) + hw0 + t] = q;
    }
#pragma unroll
    for (int off = 32; off > 0; off >>= 1) lsum += __shfl_down(lsum, off);
    if (l == 0) red[wv] = lsum;
    __syncthreads();
    if (tid == 0) atomicAdd(lossp, red[0] + red[1] + red[2] + red[3]);
}

extern "C" void kernel_launch(void* const* d_in, const int* in_sizes, int n_in,
                              void* d_out, int out_size, void* d_ws, size_t ws_size,
                              hipStream_t stream) {
    const float* x   = (const float*)d_in[0];
    const float* emb = (const float*)d_in[1];
    float* out = (float*)d_out;
    char* ws = (char*)d_ws;
    int*   hist  = (int*)(ws + WS_HIST);
    float* lossp = (float*)(ws + WS_LOSS);
    float* w2    = (float*)(ws + WS_W2);

    if (ws_size >= WS_NEED) {
        unsigned short* wpack = (unsigned short*)(ws + WS_WPK);
        split_w<<<1024, 64, 0, stream>>>(emb, wpack, w2, hist, lossp);
        vq_fused7<<<512, 512, 0, stream>>>(x, emb, wpack, w2, out, hist, lossp);
    } else {
        hipMemsetAsync(d_ws, 0, 4608, stream);
        w2_kernel<<<4, 256, 0, stream>>>(emb, w2);
        vq_main<<<1024, 256, 0, stream>>>(x, emb, out, hist, lossp, w2);
    }
    finalize_kernel<<<1, 1024, 0, stream>>>(hist, lossp, out);
}